// Round 9
// baseline (26.659 us; speedup 1.0000x reference)
//
#include <hip/hip_runtime.h>
#include <float.h>

#define H_IN 224
#define W_IN 224
#define H_T  240
#define W_T  240
#define S1   17
#define S2   17
#define NS   (S1*S2)          // 289
#define NB   8
#define NPIX (H_IN*W_IN)      // 50176
#define TPIX (H_T*W_T)        // 57600
#define RG   8                // row-groups per sample-shift
#define ROWS_PER_BLOCK (H_IN/RG)          // 28
#define ROWS_PER_WAVE  (ROWS_PER_BLOCK/4) // 7
#define PB   (NPIX/256)       // 196 copy-blocks per sample

// ws float layout:
//   part : [B][S1][RG][S2]  -> 8*17*8*17 = 18496 floats @ 0
//   fpart: [B][RG]          -> 64 floats @ 18496
#define WS_PART  0
#define WS_FPART 18496

// ---------------- kernel 1: corr partials + fused f(l) partials ----------------
// block = (b, i, rg). 256 threads = 4 waves; each wave does 7 rows; lanes 0..55
// each own 4 consecutive x (float4). 6 wide loads per row feed 68 FMAs.
// ALL array indices are literal constants (macro-unrolled) to guarantee SROA
// into registers — round-5/6 profiles showed VGPR_Count=32, proving the
// compiler had demoted t[]/acc[] (scratch or load-splitting), tripling L1 ops.
__global__ __launch_bounds__(256) void corr_f_kernel(const float* __restrict__ logits,
                                                     const float* __restrict__ targ,
                                                     float* __restrict__ ws) {
    int bid  = blockIdx.x;              // b*S1*RG + i*RG + rg
    int rg   = bid % RG;
    int i    = (bid / RG) % S1;
    int b    = bid / (RG * S1);
    int tid  = threadIdx.x;
    int lane = tid & 63;
    int w    = tid >> 6;
    bool active = lane < (W_IN / 4);    // 56 active lanes

    float acc[S2] = {0.f,0.f,0.f,0.f,0.f,0.f,0.f,0.f,0.f,
                     0.f,0.f,0.f,0.f,0.f,0.f,0.f,0.f};
    float fs = 0.f;

    const float* Lb = logits + b * NPIX;
    const float* Tb = targ   + b * TPIX;
    const int y0 = rg * ROWS_PER_BLOCK + w * ROWS_PER_WAVE;
    const bool do_f = (i == 0);

    for (int r = 0; r < ROWS_PER_WAVE; ++r) {
        int y = y0 + r;
        if (active) {
            const float4 l4 = *(const float4*)(Lb + y * W_IN + lane * 4);
            const float* Tr = Tb + (y + i) * W_T + lane * 4;
            const float4 t0 = *(const float4*)(Tr);
            const float4 t1 = *(const float4*)(Tr + 4);
            const float4 t2 = *(const float4*)(Tr + 8);
            const float4 t3 = *(const float4*)(Tr + 12);
            const float4 t4 = *(const float4*)(Tr + 16);
            // constant-index-only local array -> guaranteed SROA to registers
            float T[20];
            T[0]=t0.x;  T[1]=t0.y;  T[2]=t0.z;  T[3]=t0.w;
            T[4]=t1.x;  T[5]=t1.y;  T[6]=t1.z;  T[7]=t1.w;
            T[8]=t2.x;  T[9]=t2.y;  T[10]=t2.z; T[11]=t2.w;
            T[12]=t3.x; T[13]=t3.y; T[14]=t3.z; T[15]=t3.w;
            T[16]=t4.x; T[17]=t4.y; T[18]=t4.z; T[19]=t4.w;

#define ROWFMA(J)                                   \
            {   float s_ = acc[J];                  \
                s_ = fmaf(l4.x, T[J],     s_);      \
                s_ = fmaf(l4.y, T[(J)+1], s_);      \
                s_ = fmaf(l4.z, T[(J)+2], s_);      \
                s_ = fmaf(l4.w, T[(J)+3], s_);      \
                acc[J] = s_; }
            ROWFMA(0)  ROWFMA(1)  ROWFMA(2)  ROWFMA(3)
            ROWFMA(4)  ROWFMA(5)  ROWFMA(6)  ROWFMA(7)
            ROWFMA(8)  ROWFMA(9)  ROWFMA(10) ROWFMA(11)
            ROWFMA(12) ROWFMA(13) ROWFMA(14) ROWFMA(15)
            ROWFMA(16)
#undef ROWFMA

            if (do_f) {
                float v0 = l4.x, v1 = l4.y, v2 = l4.z, v3 = l4.w;
                fs += fmaxf(v0, 0.f) + __logf(1.f + __expf(-fabsf(v0)));
                fs += fmaxf(v1, 0.f) + __logf(1.f + __expf(-fabsf(v1)));
                fs += fmaxf(v2, 0.f) + __logf(1.f + __expf(-fabsf(v2)));
                fs += fmaxf(v3, 0.f) + __logf(1.f + __expf(-fabsf(v3)));
            }
        }
    }

    __shared__ float red[4][S2];
    __shared__ float redf[4];

    // butterfly reduce each acc[J] across the wave; literal indices only
#define RED17(J)                                    \
    {   float v_ = acc[J];                          \
        v_ += __shfl_xor(v_, 32, 64);               \
        v_ += __shfl_xor(v_, 16, 64);               \
        v_ += __shfl_xor(v_,  8, 64);               \
        v_ += __shfl_xor(v_,  4, 64);               \
        v_ += __shfl_xor(v_,  2, 64);               \
        v_ += __shfl_xor(v_,  1, 64);               \
        if (lane == 0) red[w][J] = v_; }
    RED17(0)  RED17(1)  RED17(2)  RED17(3)
    RED17(4)  RED17(5)  RED17(6)  RED17(7)
    RED17(8)  RED17(9)  RED17(10) RED17(11)
    RED17(12) RED17(13) RED17(14) RED17(15)
    RED17(16)
#undef RED17

    if (do_f) {
        fs += __shfl_xor(fs, 32, 64);
        fs += __shfl_xor(fs, 16, 64);
        fs += __shfl_xor(fs,  8, 64);
        fs += __shfl_xor(fs,  4, 64);
        fs += __shfl_xor(fs,  2, 64);
        fs += __shfl_xor(fs,  1, 64);
        if (lane == 0) redf[w] = fs;
    }
    __syncthreads();
    if (tid < S2) {
        float v = red[0][tid] + red[1][tid] + red[2][tid] + red[3][tid];
        ws[WS_PART + ((b * S1 + i) * RG + rg) * S2 + tid] = v;
    }
    if (do_f && tid == 0)
        ws[WS_FPART + b * RG + rg] = redf[0] + redf[1] + redf[2] + redf[3];
}

// ---------------- kernel 2: argmax + copy + loss ----------------
__device__ __forceinline__ float part_sum(const float* __restrict__ pp) {
    float v = 0.f;
#pragma unroll
    for (int k = 0; k < RG; ++k) v += pp[k * S2];
    return v;
}

__device__ __forceinline__ void argmax_for(const float* __restrict__ part, int bb,
                                           int tid, int lane, int w,
                                           float* s_v, int* s_i,
                                           float& o_v, int& o_i) {
    float bv = -FLT_MAX;
    int   bs = NS;
    for (int s = tid; s < NS; s += 256) {
        const float* pp = part + ((bb * S1 + s / S2) * RG) * S2 + (s % S2);
        float v = part_sum(pp);
        if (v > bv) { bv = v; bs = s; } // s ascending -> earliest tie kept
    }
#pragma unroll
    for (int off = 32; off > 0; off >>= 1) {
        float ov = __shfl_down(bv, off, 64);
        int   oi = __shfl_down(bs, off, 64);
        if (ov > bv || (ov == bv && oi < bs)) { bv = ov; bs = oi; }
    }
    if (lane == 0) { s_v[w] = bv; s_i[w] = bs; }
    __syncthreads();
    if (tid == 0) {
        float fv = s_v[0]; int fi = s_i[0];
#pragma unroll
        for (int k = 1; k < 4; ++k) {
            if (s_v[k] > fv || (s_v[k] == fv && s_i[k] < fi)) { fv = s_v[k]; fi = s_i[k]; }
        }
        s_v[4] = fv; s_i[4] = fi;
    }
    __syncthreads();
    o_v = s_v[4];
    o_i = s_i[4];
}

__device__ __forceinline__ void argmax_all8(const float* __restrict__ part,
                                            int lane, int w,
                                            float* s_v8, int* s_i8) {
#pragma unroll
    for (int pass = 0; pass < 2; ++pass) {
        int bb = w + pass * 4;
        float bv2 = -FLT_MAX;
        int   bs2 = NS;
        for (int s = lane; s < NS; s += 64) {
            const float* pp = part + ((bb * S1 + s / S2) * RG) * S2 + (s % S2);
            float v = part_sum(pp);
            if (v > bv2) { bv2 = v; bs2 = s; }
        }
#pragma unroll
        for (int off = 32; off > 0; off >>= 1) {
            float ov = __shfl_down(bv2, off, 64);
            int   oi = __shfl_down(bs2, off, 64);
            if (ov > bv2 || (ov == bv2 && oi < bs2)) { bv2 = ov; bs2 = oi; }
        }
        if (lane == 0) { s_v8[bb] = bv2; s_i8[bb] = bs2; }
    }
    __syncthreads();
}

__global__ __launch_bounds__(256) void finish_kernel(const float* __restrict__ targ,
                                                     const float* __restrict__ ws,
                                                     float* __restrict__ out) {
    int blk = blockIdx.x;               // b*PB + p
    int p   = blk % PB;
    int b   = blk / PB;
    int tid = threadIdx.x;
    int lane = tid & 63;
    int w    = tid >> 6;

    const float* part  = ws + WS_PART;
    const float* fpart = ws + WS_FPART;

    __shared__ float s_v[5];
    __shared__ int   s_i[5];
    __shared__ float s_v8[NB];
    __shared__ int   s_i8[NB];

    int best;
    if (blk == 0) {
        argmax_all8(part, lane, w, s_v8, s_i8);
        if (tid == 0) {
            float total = 0.f;
#pragma unroll
            for (int bb = 0; bb < NB; ++bb) {
                float F = 0.f;
#pragma unroll
                for (int k = 0; k < RG; ++k) F += fpart[bb * RG + k];
                total += (F - s_v8[bb]) * (1.0f / (float)NPIX);
            }
            out[0] = total;
        }
        best = s_i8[0];
    } else {
        float bv;
        argmax_for(part, b, tid, lane, w, s_v, s_i, bv, best);
    }

    int pix = p * 256 + tid;            // < 50176 exactly
    int y = pix / W_IN;
    int x = pix - y * W_IN;
    int i = best / S2;
    int j = best - i * S2;
    out[1 + b * NPIX + pix] = targ[b * TPIX + (y + i) * W_T + (x + j)];
}

extern "C" void kernel_launch(void* const* d_in, const int* in_sizes, int n_in,
                              void* d_out, int out_size, void* d_ws, size_t ws_size,
                              hipStream_t stream) {
    const float* logits = (const float*)d_in[0];   // [8,1,224,224]
    const float* targ   = (const float*)d_in[1];   // [8,1,240,240]
    float* out = (float*)d_out;                    // [1 + 8*224*224]
    float* ws  = (float*)d_ws;

    corr_f_kernel<<<NB * S1 * RG, 256, 0, stream>>>(logits, targ, ws);
    finish_kernel<<<NB * PB, 256, 0, stream>>>(targ, ws, out);
}